// Round 7
// baseline (113.016 us; speedup 1.0000x reference)
//
#include <hip/hip_runtime.h>
#include <hip/hip_bf16.h>

#define NROWS 4096
#define DIM   768
#define NKT   12          // 768 / 64 K-tiles (even)

typedef __attribute__((ext_vector_type(8))) short short8;
typedef __attribute__((ext_vector_type(4))) float f32x4;

#define GAS(p) ((const __attribute__((address_space(1))) void*)(p))
#define SAS(p) ((__attribute__((address_space(3))) void*)(p))

// fp32 -> bf16 round-to-nearest-even
__device__ __forceinline__ unsigned short f2bf(float x) {
    unsigned int u = __builtin_bit_cast(unsigned int, x);
    u += 0x7fffu + ((u >> 16) & 1u);
    return (unsigned short)(u >> 16);
}

// ---------------- Kernel 1: L2-normalize rows -> bf16; also zero rowsum ----------------
__global__ __launch_bounds__(256) void k_norm(const float* __restrict__ f1,
                                              const float* __restrict__ f2,
                                              unsigned short* __restrict__ n1,
                                              unsigned short* __restrict__ n2,
                                              float* __restrict__ rowsum) {
    int b = blockIdx.x;
    int wid = threadIdx.x >> 6, lane = threadIdx.x & 63;
    int rowidx = b * 4 + wid;                     // 0..8191, wave-uniform
    const float* src = (rowidx < NROWS) ? f1 : f2;
    unsigned short* dst = (rowidx < NROWS) ? n1 : n2;
    int row = rowidx & (NROWS - 1);
    const float4* srow = (const float4*)(src + (size_t)row * DIM);
    float4 v[3];
    float ss = 0.f;
#pragma unroll
    for (int r = 0; r < 3; ++r) {
        v[r] = srow[lane + 64 * r];
        ss += v[r].x * v[r].x + v[r].y * v[r].y + v[r].z * v[r].z + v[r].w * v[r].w;
    }
#pragma unroll
    for (int off = 32; off; off >>= 1) ss += __shfl_xor(ss, off);
    float inv = 1.0f / fmaxf(sqrtf(ss), 1e-8f);
    ushort4* drow = (ushort4*)(dst + (size_t)row * DIM);
#pragma unroll
    for (int r = 0; r < 3; ++r) {
        ushort4 o;
        o.x = f2bf(v[r].x * inv);
        o.y = f2bf(v[r].y * inv);
        o.z = f2bf(v[r].z * inv);
        o.w = f2bf(v[r].w * inv);
        drow[lane + 64 * r] = o;
    }
    if (b == 0) {                                  // zero rowsum (4096 floats)
        float4 z = {0.f, 0.f, 0.f, 0.f};
#pragma unroll
        for (int i = 0; i < 4; ++i) ((float4*)rowsum)[threadIdx.x + 256 * i] = z;
    }
}

// ---------------- Kernel 2: 128x128-tile bf16 MFMA GEMM + fused exp/row-sum ----------------
// 256 threads = 4 waves (2x2), per-wave output 64x64. BK=64, dbuf LDS 64 KiB -> 2 blocks/CU
// (the R6 post-mortem lever: inter-block overlap fills barrier/prologue bubbles, m114).
// Per K-tile: 2 phases x 16 MFMA/wave; counted vmcnt(8) (8 STG/tile, 2 tiles in flight);
// T2 swizzle unchanged: 128 B rows, byte_in_row ^= ((row&7)<<4), both-sides involution.

#define BARRIER __builtin_amdgcn_s_barrier()
#define WAIT_LGKM0 do { asm volatile("s_waitcnt lgkmcnt(0)" ::: "memory"); \
                        __builtin_amdgcn_sched_barrier(0); } while (0)
#define WAIT_VM8   do { asm volatile("s_waitcnt vmcnt(8)" ::: "memory"); \
                        __builtin_amdgcn_sched_barrier(0); } while (0)
#define PRIO1 __builtin_amdgcn_s_setprio(1)
#define PRIO0 __builtin_amdgcn_s_setprio(0)

__global__ __launch_bounds__(256, 2) void k_gemm_lse(const unsigned short* __restrict__ n1,
                                                     const unsigned short* __restrict__ n2,
                                                     float* __restrict__ rowsum,
                                                     float* __restrict__ diag) {
    __shared__ alignas(16) char ldsbuf[65536];
    char* ldsc = (char*)ldsbuf;

    // XCD-aware bijective swizzle (1024 % 8 == 0)
    int wg = blockIdx.x;
    int swz = (wg & 7) * 128 + (wg >> 3);
    int bi = swz >> 5;            // 32 i-tiles
    int bj = swz & 31;            // 32 j-tiles

    int tid = threadIdx.x;
    int wid = tid >> 6;
    int lane = tid & 63;
    int l15 = lane & 15, lk = lane >> 4;
    int wr = wid >> 1, wc = wid & 1;   // 2x2 wave grid, wave-tile 64x64

    const unsigned short* abase = n1 + (size_t)bi * 128 * DIM;
    const unsigned short* bbase = n2 + (size_t)bj * 128 * DIM;

    // staging: pre-swizzled global source, linear LDS dest (rule 21).
    // per STG1 call: 256 thr x 16 B = 4 KB = 32 rows; row-in-chunk = tid>>3, slot = tid&7.
    const int stoff = (tid >> 3) * DIM + (((tid & 7) ^ ((tid >> 3) & 7)) * 8);

    // ds_read per-lane offsets: addr = rowbase*128 + l15*128 + (kslot*16 ^ ((row&7)<<4))
    const int swzl = (lane & 7) << 4;
    const int lko0 = l15 * 128 + ((lk * 16) ^ swzl);          // kstep 0
    const int lko1 = l15 * 128 + (((64 + lk * 16)) ^ swzl);   // kstep 1

    // LDS regions: buf b: A = [128][128B] at b*32768, B at b*32768+16384.
    char* LAp[2] = { ldsc + wr * 8192,          ldsc + 32768 + wr * 8192 };
    char* LBp[2] = { ldsc + 16384 + wc * 8192,  ldsc + 32768 + 16384 + wc * 8192 };

#define STG1(b, isB, base, chunk, kt) do { \
    const unsigned short* _s = (base) + ((chunk) * 32) * DIM + (kt) * 64 + stoff; \
    char* _d = ldsc + (b) * 32768 + (isB) * 16384 + (chunk) * 4096 + tid * 16; \
    __builtin_amdgcn_global_load_lds(GAS(_s), SAS(_d), 16, 0, 0); \
} while (0)

#define STG8(b, kt) do { \
    STG1(b, 0, abase, 0, kt); STG1(b, 0, abase, 1, kt); \
    STG1(b, 0, abase, 2, kt); STG1(b, 0, abase, 3, kt); \
    STG1(b, 1, bbase, 0, kt); STG1(b, 1, bbase, 1, kt); \
    STG1(b, 1, bbase, 2, kt); STG1(b, 1, bbase, 3, kt); \
} while (0)

// load A-frags {q*2, q*2+1} (rows q*32 + m*16 + l15 of this wave's 64-row half)
#define LDA2(b, q, areg) do { _Pragma("unroll") for (int m = 0; m < 2; ++m) { \
    const char* _p = LAp[b] + ((q) * 32 + m * 16) * 128; \
    areg[m][0] = *(const short8*)(_p + lko0); \
    areg[m][1] = *(const short8*)(_p + lko1); } } while (0)

#define LDB4(b, breg) do { _Pragma("unroll") for (int n = 0; n < 4; ++n) { \
    const char* _p = LBp[b] + n * 16 * 128; \
    breg[n][0] = *(const short8*)(_p + lko0); \
    breg[n][1] = *(const short8*)(_p + lko1); } } while (0)

#define MMH(qm, areg, breg) do { _Pragma("unroll") for (int m = 0; m < 2; ++m) \
    _Pragma("unroll") for (int n = 0; n < 4; ++n) { \
    f32x4* _c = &acc[(qm) * 2 + m][n]; \
    *_c = __builtin_amdgcn_mfma_f32_16x16x32_bf16(areg[m][0], breg[n][0], *_c, 0, 0, 0); \
    *_c = __builtin_amdgcn_mfma_f32_16x16x32_bf16(areg[m][1], breg[n][1], *_c, 0, 0, 0); } } while (0)

    short8 a0A[2][2], a1A[2][2], aB[2][2], b0[4][2], b1[4][2];
    f32x4 acc[4][4] = {};

    // Prologue: stage tile0 -> buf0, tile1 -> buf1; wait tile0; initial read-ahead.
    STG8(0, 0);
    STG8(1, 1);
    WAIT_VM8;          // tile0 landed (tile1's 8 may remain in flight)
    BARRIER;
    LDA2(0, 0, a0A); LDB4(0, b0);

    for (int t = 0; t < NKT; t += 2) {
        int t2 = (t + 2 < NKT) ? t + 2 : t + 2 - NKT;   // wrap: staged-but-never-read
        int t3 = (t + 3 < NKT) ? t + 3 : t + 3 - NKT;
        // ---- tile t (buf0) ----
        // p0: consume {a0A, b0}; issue aB
        WAIT_LGKM0;                      // a0A, b0 complete
        LDA2(0, 1, aB);
        PRIO1; MMH(0, a0A, b0); PRIO0;
        WAIT_LGKM0;                      // aB complete BEFORE barrier (DMA-overwrite guard)
        BARRIER;
        // p1: stage t+2 into buf0; consume {aB, b0}; after vmcnt(8) read-ahead tile t+1
        STG8(0, t2);
        PRIO1; MMH(1, aB, b0); PRIO0;
        WAIT_VM8;                        // tile t+1 fully landed; t+2's 8 stay in flight
        LDA2(1, 0, a1A); LDB4(1, b1);
        BARRIER;
        // ---- tile t+1 (buf1) ----
        WAIT_LGKM0;
        LDA2(1, 1, aB);
        PRIO1; MMH(0, a1A, b1); PRIO0;
        WAIT_LGKM0;
        BARRIER;
        STG8(1, t3);
        PRIO1; MMH(1, aB, b1); PRIO0;
        WAIT_VM8;                        // tile t+2 fully landed; t+3's 8 stay in flight
        LDA2(0, 0, a0A); LDB4(0, b0);    // dead on last iteration (wrapped data, valid LDS)
        BARRIER;
    }

    __syncthreads();   // drains remaining vmcnt/lgkmcnt before epilogue

    // Epilogue. C/D layout: col = l15, row = lk*4 + r (per 16x16 frag).
    const bool dblk = (bi == bj);
    const int rowb = bi * 128 + wr * 64;
    const int colb = bj * 128 + wc * 64;
#pragma unroll
    for (int mi = 0; mi < 4; ++mi) {
#pragma unroll
        for (int r = 0; r < 4; ++r) {
            float s = 0.f;
            int gi = rowb + mi * 16 + lk * 4 + r;
#pragma unroll
            for (int ni = 0; ni < 4; ++ni) {
                float v = acc[mi][ni][r] * 20.0f;    // 1/TEMP
                s += __expf(v);
                if (dblk) {
                    int gj = colb + ni * 16 + l15;
                    if (gi == gj) diag[gi] = v;
                }
            }
#pragma unroll
            for (int off = 1; off < 16; off <<= 1) s += __shfl_xor(s, off);
            if (l15 == 0) atomicAdd(rowsum + gi, s);
        }
    }
}

// ---------------- Kernel 3: loss = mean(log(rowsum) - diag) ----------------
__global__ __launch_bounds__(1024) void k_final(const float* __restrict__ rowsum,
                                                const float* __restrict__ diag,
                                                float* __restrict__ out) {
    int tid = threadIdx.x;
    float s = 0.f;
#pragma unroll
    for (int i = 0; i < 4; ++i) {
        int idx = tid + 1024 * i;
        s += logf(rowsum[idx]) - diag[idx];
    }
#pragma unroll
    for (int off = 32; off; off >>= 1) s += __shfl_xor(s, off);
    __shared__ float red[16];
    if ((tid & 63) == 0) red[tid >> 6] = s;
    __syncthreads();
    if (tid == 0) {
        float tot = 0.f;
#pragma unroll
        for (int i = 0; i < 16; ++i) tot += red[i];
        out[0] = tot * (1.0f / NROWS);
    }
}

extern "C" void kernel_launch(void* const* d_in, const int* in_sizes, int n_in,
                              void* d_out, int out_size, void* d_ws, size_t ws_size,
                              hipStream_t stream) {
    const float* f1 = (const float*)d_in[0];
    const float* f2 = (const float*)d_in[1];
    float* out = (float*)d_out;

    char* ws = (char*)d_ws;                       // layout: n1 | n2 | rowsum | diag
    unsigned short* n1 = (unsigned short*)ws;
    unsigned short* n2 = n1 + (size_t)NROWS * DIM;
    float* rowsum = (float*)(ws + 2 * (size_t)NROWS * DIM * sizeof(unsigned short));
    float* diag = rowsum + NROWS;

    k_norm<<<2048, 256, 0, stream>>>(f1, f2, n1, n2, rowsum);
    k_gemm_lse<<<1024, 256, 0, stream>>>(n1, n2, rowsum, diag);
    k_final<<<1, 1024, 0, stream>>>(rowsum, diag, out);
}

// Round 8
// 109.659 us; speedup vs baseline: 1.0306x; 1.0306x over previous
//
#include <hip/hip_runtime.h>
#include <hip/hip_bf16.h>

#define NROWS 4096
#define DIM   768
#define NKT   6           // 768 / 128 K-tiles (even)

typedef __attribute__((ext_vector_type(4))) float f32x4;

#define GAS(p) ((const __attribute__((address_space(1))) void*)(p))
#define SAS(p) ((__attribute__((address_space(3))) void*)(p))

// ---------------- Kernel 1: L2-normalize rows -> fp8 e4m3 (scaled x8); zero rowsum ----------------
// one wave per row; rows scaled by 8 before quantization (keeps elements in e4m3 normal range);
// GEMM epilogue divides by 64. Norm computed in fp32 from original data (matches reference).
__global__ __launch_bounds__(256) void k_norm(const float* __restrict__ f1,
                                              const float* __restrict__ f2,
                                              unsigned char* __restrict__ n1,
                                              unsigned char* __restrict__ n2,
                                              float* __restrict__ rowsum) {
    int b = blockIdx.x;
    int wid = threadIdx.x >> 6, lane = threadIdx.x & 63;
    int rowidx = b * 4 + wid;                     // 0..8191, wave-uniform
    const float* src = (rowidx < NROWS) ? f1 : f2;
    unsigned char* dst = (rowidx < NROWS) ? n1 : n2;
    int row = rowidx & (NROWS - 1);
    const float4* srow = (const float4*)(src + (size_t)row * DIM);
    float4 v[3];
    float ss = 0.f;
#pragma unroll
    for (int r = 0; r < 3; ++r) {
        v[r] = srow[lane + 64 * r];               // elements k = 4*lane + 256*r + {0..3}
        ss += v[r].x * v[r].x + v[r].y * v[r].y + v[r].z * v[r].z + v[r].w * v[r].w;
    }
#pragma unroll
    for (int off = 32; off; off >>= 1) ss += __shfl_xor(ss, off);
    float inv8 = 8.0f / fmaxf(sqrtf(ss), 1e-8f);  // x8 scale folded into the normalizer
    unsigned int* drow = (unsigned int*)(dst + (size_t)row * DIM);
#pragma unroll
    for (int r = 0; r < 3; ++r) {
        int w = __builtin_amdgcn_cvt_pk_fp8_f32(v[r].x * inv8, v[r].y * inv8, 0, false);
        w = __builtin_amdgcn_cvt_pk_fp8_f32(v[r].z * inv8, v[r].w * inv8, w, true);
        drow[lane + 64 * r] = (unsigned int)w;    // bytes 4*lane + 256*r .. +3
    }
    if (b == 0) {                                  // zero rowsum (4096 floats)
        float4 z = {0.f, 0.f, 0.f, 0.f};
#pragma unroll
        for (int i = 0; i < 4; ++i) ((float4*)rowsum)[threadIdx.x + 256 * i] = z;
    }
}

// ---------------- Kernel 2: 128x128-tile fp8 MFMA GEMM + fused exp/row-sum ----------------
// R7 structure byte-identical (128 B LDS rows, 16B-slot XOR swizzle, STG8/vmcnt(8), 2-phase
// + read-ahead, 2 blocks/CU), reinterpreted as fp8: each 128 B row = K=128 elements, NKT=6.
// Frags are ds_read_b64 (8 fp8); A and B use identical lane->k addressing so any internal
// k-permutation of the MFMA cancels. mfma_f32_16x16x32_fp8_fp8 runs at bf16 rate; all memory
// traffic (HBM fetch, LDS bytes) halves vs bf16 -- the R7-measured bottleneck.

#define BARRIER __builtin_amdgcn_s_barrier()
#define WAIT_LGKM0 do { asm volatile("s_waitcnt lgkmcnt(0)" ::: "memory"); \
                        __builtin_amdgcn_sched_barrier(0); } while (0)
#define WAIT_VM8   do { asm volatile("s_waitcnt vmcnt(8)" ::: "memory"); \
                        __builtin_amdgcn_sched_barrier(0); } while (0)
#define PRIO1 __builtin_amdgcn_s_setprio(1)
#define PRIO0 __builtin_amdgcn_s_setprio(0)

__global__ __launch_bounds__(256, 2) void k_gemm_lse(const unsigned char* __restrict__ n1,
                                                     const unsigned char* __restrict__ n2,
                                                     float* __restrict__ rowsum,
                                                     float* __restrict__ diag) {
    __shared__ alignas(16) char ldsbuf[65536];
    char* ldsc = (char*)ldsbuf;

    // XCD-aware bijective swizzle (1024 % 8 == 0)
    int wg = blockIdx.x;
    int swz = (wg & 7) * 128 + (wg >> 3);
    int bi = swz >> 5;            // 32 i-tiles
    int bj = swz & 31;            // 32 j-tiles

    int tid = threadIdx.x;
    int wid = tid >> 6;
    int lane = tid & 63;
    int l15 = lane & 15, lk = lane >> 4;
    int wr = wid >> 1, wc = wid & 1;   // 2x2 wave grid, wave-tile 64x64

    const unsigned char* abase = n1 + (size_t)bi * 128 * DIM;
    const unsigned char* bbase = n2 + (size_t)bj * 128 * DIM;

    // staging: pre-swizzled global source, linear LDS dest (rule 21).
    // dest row = chunk*32 + (tid>>3) (128 B rows), dest 16B-slot = tid&7;
    // source slot = (tid&7) ^ (row&7); element==byte for fp8.
    const int stoff = (tid >> 3) * DIM + (((tid & 7) ^ ((tid >> 3) & 7)) * 16);

    // frag addressing: instr j (k = j*32 + lk*8 + e): slot s = 2j + (lk>>1), swizzled s^(l15&7),
    // within-slot byte (lk&1)*8. b64 never crosses a 16B swizzle unit.
    const int h7 = l15 & 7;
    const int fbase = l15 * 128 + (lk & 1) * 8;
    int slotx[4];
#pragma unroll
    for (int j = 0; j < 4; ++j) slotx[j] = ((2 * j + (lk >> 1)) ^ h7) * 16;

    // LDS regions: buf b: A = [128 rows][128B] at b*32768, B at b*32768+16384.
    char* LAp[2] = { ldsc + wr * 8192,          ldsc + 32768 + wr * 8192 };
    char* LBp[2] = { ldsc + 16384 + wc * 8192,  ldsc + 32768 + 16384 + wc * 8192 };

#define STG1(b, isB, base, chunk, kt) do { \
    const unsigned char* _s = (base) + ((chunk) * 32) * DIM + (kt) * 128 + stoff; \
    char* _d = ldsc + (b) * 32768 + (isB) * 16384 + (chunk) * 4096 + tid * 16; \
    __builtin_amdgcn_global_load_lds(GAS(_s), SAS(_d), 16, 0, 0); \
} while (0)

#define STG8(b, kt) do { \
    STG1(b, 0, abase, 0, kt); STG1(b, 0, abase, 1, kt); \
    STG1(b, 0, abase, 2, kt); STG1(b, 0, abase, 3, kt); \
    STG1(b, 1, bbase, 0, kt); STG1(b, 1, bbase, 1, kt); \
    STG1(b, 1, bbase, 2, kt); STG1(b, 1, bbase, 3, kt); \
} while (0)

// load A[4][2] and B[4][2] longs for j-pair jp (j = jp*2 + jj): 32 ds_read_b64
#define LDF(b, jp, Areg, Breg) do { \
    _Pragma("unroll") for (int m = 0; m < 4; ++m) \
    _Pragma("unroll") for (int jj = 0; jj < 2; ++jj) { \
        Areg[m][jj] = *(const long*)(LAp[b] + m * 2048 + fbase + slotx[(jp) * 2 + jj]); \
        Breg[m][jj] = *(const long*)(LBp[b] + m * 2048 + fbase + slotx[(jp) * 2 + jj]); \
    } } while (0)

// 32 MFMA: quadrant-complete over m,n for one j-pair
#define MM32(Areg, Breg) do { _Pragma("unroll") for (int m = 0; m < 4; ++m) \
    _Pragma("unroll") for (int n = 0; n < 4; ++n) \
    _Pragma("unroll") for (int jj = 0; jj < 2; ++jj) { \
    f32x4* _c = &acc[m][n]; \
    *_c = __builtin_amdgcn_mfma_f32_16x16x32_fp8_fp8(Areg[m][jj], Breg[n][jj], *_c, 0, 0, 0); \
    } } while (0)

    long A0[4][2], B0[4][2], A1[4][2], B1[4][2];
    f32x4 acc[4][4] = {};

    // Prologue: stage tile0 -> buf0, tile1 -> buf1; wait tile0; initial read-ahead (j01 of tile0).
    STG8(0, 0);
    STG8(1, 1);
    WAIT_VM8;          // tile0 landed (tile1's 8 may remain in flight)
    BARRIER;
    LDF(0, 0, A0, B0);

    for (int t = 0; t < NKT; t += 2) {
        int t2 = (t + 2 < NKT) ? t + 2 : t + 2 - NKT;   // wrap: staged-but-never-read
        int t3 = (t + 3 < NKT) ? t + 3 : t + 3 - NKT;
        // ---- tile t (buf0) ----
        WAIT_LGKM0;                      // {A0,B0} (j01) complete
        LDF(0, 1, A1, B1);               // issue j23
        PRIO1; MM32(A0, B0); PRIO0;
        WAIT_LGKM0;                      // j23 complete BEFORE barrier (DMA-overwrite guard)
        BARRIER;
        STG8(0, t2);
        PRIO1; MM32(A1, B1); PRIO0;
        WAIT_VM8;                        // tile t+1 fully landed; t+2's 8 stay in flight
        LDF(1, 0, A0, B0);               // read-ahead j01 of tile t+1
        BARRIER;
        // ---- tile t+1 (buf1) ----
        WAIT_LGKM0;
        LDF(1, 1, A1, B1);
        PRIO1; MM32(A0, B0); PRIO0;
        WAIT_LGKM0;
        BARRIER;
        STG8(1, t3);
        PRIO1; MM32(A1, B1); PRIO0;
        WAIT_VM8;                        // tile t+2 fully landed; t+3's 8 stay in flight
        LDF(0, 0, A0, B0);               // dead on last iteration (wrapped data, valid LDS)
        BARRIER;
    }

    __syncthreads();   // drains remaining vmcnt/lgkmcnt before epilogue

    // Epilogue. C/D layout: col = l15, row = lk*4 + r (dtype-independent, m121/m123).
    // acc = sum of (8a)(8b) = 64*cossim -> logits = acc * (20/64).
    const bool dblk = (bi == bj);
    const int rowb = bi * 128 + wr * 64;
    const int colb = bj * 128 + wc * 64;
#pragma unroll
    for (int mi = 0; mi < 4; ++mi) {
#pragma unroll
        for (int r = 0; r < 4; ++r) {
            float s = 0.f;
            int gi = rowb + mi * 16 + lk * 4 + r;
#pragma unroll
            for (int ni = 0; ni < 4; ++ni) {
                float v = acc[mi][ni][r] * (20.0f / 64.0f);
                s += __expf(v);
                if (dblk) {
                    int gj = colb + ni * 16 + l15;
                    if (gi == gj) diag[gi] = v;
                }
            }
#pragma unroll
            for (int off = 1; off < 16; off <<= 1) s += __shfl_xor(s, off);
            if (l15 == 0) atomicAdd(rowsum + gi, s);
        }
    }
}

// ---------------- Kernel 3: loss = mean(log(rowsum) - diag) ----------------
__global__ __launch_bounds__(1024) void k_final(const float* __restrict__ rowsum,
                                                const float* __restrict__ diag,
                                                float* __restrict__ out) {
    int tid = threadIdx.x;
    float s = 0.f;
#pragma unroll
    for (int i = 0; i < 4; ++i) {
        int idx = tid + 1024 * i;
        s += logf(rowsum[idx]) - diag[idx];
    }
#pragma unroll
    for (int off = 32; off; off >>= 1) s += __shfl_xor(s, off);
    __shared__ float red[16];
    if ((tid & 63) == 0) red[tid >> 6] = s;
    __syncthreads();
    if (tid == 0) {
        float tot = 0.f;
#pragma unroll
        for (int i = 0; i < 16; ++i) tot += red[i];
        out[0] = tot * (1.0f / NROWS);
    }
}

extern "C" void kernel_launch(void* const* d_in, const int* in_sizes, int n_in,
                              void* d_out, int out_size, void* d_ws, size_t ws_size,
                              hipStream_t stream) {
    const float* f1 = (const float*)d_in[0];
    const float* f2 = (const float*)d_in[1];
    float* out = (float*)d_out;

    char* ws = (char*)d_ws;                       // layout: n1 | n2 | rowsum | diag
    unsigned char* n1 = (unsigned char*)ws;
    unsigned char* n2 = n1 + (size_t)NROWS * DIM;
    float* rowsum = (float*)(ws + 2 * (size_t)NROWS * DIM);
    float* diag = rowsum + NROWS;

    k_norm<<<2048, 256, 0, stream>>>(f1, f2, n1, n2, rowsum);
    k_gemm_lse<<<1024, 256, 0, stream>>>(n1, n2, rowsum, diag);
    k_final<<<1, 1024, 0, stream>>>(rowsum, diag, out);
}

// Round 9
// 100.768 us; speedup vs baseline: 1.1215x; 1.0882x over previous
//
#include <hip/hip_runtime.h>
#include <hip/hip_bf16.h>

#define NROWS 4096
#define DIM   768
#define NKT   6           // 768 / 128 K-tiles

typedef __attribute__((ext_vector_type(4))) float f32x4;

#define GAS(p) ((const __attribute__((address_space(1))) void*)(p))
#define SAS(p) ((__attribute__((address_space(3))) void*)(p))

// ---------------- Kernel 1: L2-normalize rows -> fp8 e4m3 (scaled x8); zero rowsum ----------------
__global__ __launch_bounds__(256) void k_norm(const float* __restrict__ f1,
                                              const float* __restrict__ f2,
                                              unsigned char* __restrict__ n1,
                                              unsigned char* __restrict__ n2,
                                              float* __restrict__ rowsum) {
    int b = blockIdx.x;
    int wid = threadIdx.x >> 6, lane = threadIdx.x & 63;
    int rowidx = b * 4 + wid;                     // 0..8191, wave-uniform
    const float* src = (rowidx < NROWS) ? f1 : f2;
    unsigned char* dst = (rowidx < NROWS) ? n1 : n2;
    int row = rowidx & (NROWS - 1);
    const float4* srow = (const float4*)(src + (size_t)row * DIM);
    float4 v[3];
    float ss = 0.f;
#pragma unroll
    for (int r = 0; r < 3; ++r) {
        v[r] = srow[lane + 64 * r];               // elements k = 4*lane + 256*r + {0..3}
        ss += v[r].x * v[r].x + v[r].y * v[r].y + v[r].z * v[r].z + v[r].w * v[r].w;
    }
#pragma unroll
    for (int off = 32; off; off >>= 1) ss += __shfl_xor(ss, off);
    float inv8 = 8.0f / fmaxf(sqrtf(ss), 1e-8f);  // x8 scale folded into the normalizer
    unsigned int* drow = (unsigned int*)(dst + (size_t)row * DIM);
#pragma unroll
    for (int r = 0; r < 3; ++r) {
        int w = __builtin_amdgcn_cvt_pk_fp8_f32(v[r].x * inv8, v[r].y * inv8, 0, false);
        w = __builtin_amdgcn_cvt_pk_fp8_f32(v[r].z * inv8, v[r].w * inv8, w, true);
        drow[lane + 64 * r] = (unsigned int)w;
    }
    if (b == 0) {                                  // zero rowsum (4096 floats)
        float4 z = {0.f, 0.f, 0.f, 0.f};
#pragma unroll
        for (int i = 0; i < 4; ++i) ((float4*)rowsum)[threadIdx.x + 256 * i] = z;
    }
}

// ---------------- Kernel 2: 128x128-tile fp8 MFMA GEMM + fused exp/row-sum ----------------
// m97-style high-occupancy structure (the R8 post-mortem lever): single-buffered 32 KB LDS,
// plain __syncthreads per tile, NO hand scheduling -- 4 blocks/CU (4 waves/SIMD) so inter-wave
// overlap (m114) fills the stage/barrier bubbles that capped the 2-blocks/CU variants.
// Verified pieces kept from R8: fp8 addressing/swizzle (0 conflicts), global_load_lds 16B,
// XCD swizzle, epilogue exp/reduce/atomics, x8 quantization scale.
__global__ __launch_bounds__(256, 4) void k_gemm_lse(const unsigned char* __restrict__ n1,
                                                     const unsigned char* __restrict__ n2,
                                                     float* __restrict__ rowsum,
                                                     float* __restrict__ diag) {
    __shared__ alignas(16) char ldsbuf[32768];
    char* ldsc = (char*)ldsbuf;

    // XCD-aware bijective swizzle (1024 % 8 == 0)
    int wg = blockIdx.x;
    int swz = (wg & 7) * 128 + (wg >> 3);
    int bi = swz >> 5;            // 32 i-tiles
    int bj = swz & 31;            // 32 j-tiles

    int tid = threadIdx.x;
    int wid = tid >> 6;
    int lane = tid & 63;
    int l15 = lane & 15, lk = lane >> 4;
    int wr = wid >> 1, wc = wid & 1;   // 2x2 wave grid, wave-tile 64x64

    const unsigned char* abase = n1 + (size_t)bi * 128 * DIM;
    const unsigned char* bbase = n2 + (size_t)bj * 128 * DIM;

    // staging: pre-swizzled global source, linear LDS dest (rule 21).
    // dest row = chunk*32 + (tid>>3) (128 B rows), dest 16B-slot = tid&7;
    // source slot = (tid&7) ^ (row&7); element==byte for fp8.
    const int stoff = (tid >> 3) * DIM + (((tid & 7) ^ ((tid >> 3) & 7)) * 16);

    // frag addressing (R8-verified): instr j (k = j*32 + lk*8 + e): slot = 2j + (lk>>1),
    // swizzled ^ (l15&7), within-slot byte (lk&1)*8; b64 stays inside a 16B swizzle unit.
    const int h7 = l15 & 7;
    const int fbase = l15 * 128 + (lk & 1) * 8;
    int slotx[4];
#pragma unroll
    for (int j = 0; j < 4; ++j) slotx[j] = ((2 * j + (lk >> 1)) ^ h7) * 16;

    // LDS: A [128 rows][128B] at 0 (this wave's half at wr*8192), B at 16384 (+wc*8192).
    const char* LAp = ldsc + wr * 8192;
    const char* LBp = ldsc + 16384 + wc * 8192;

#define STG1(isB, base, chunk, kt) do { \
    const unsigned char* _s = (base) + ((chunk) * 32) * DIM + (kt) * 128 + stoff; \
    char* _d = ldsc + (isB) * 16384 + (chunk) * 4096 + tid * 16; \
    __builtin_amdgcn_global_load_lds(GAS(_s), SAS(_d), 16, 0, 0); \
} while (0)

    f32x4 acc[4][4] = {};

    for (int t = 0; t < NKT; ++t) {
        STG1(0, abase, 0, t); STG1(0, abase, 1, t);
        STG1(0, abase, 2, t); STG1(0, abase, 3, t);
        STG1(1, bbase, 0, t); STG1(1, bbase, 1, t);
        STG1(1, bbase, 2, t); STG1(1, bbase, 3, t);
        __syncthreads();                 // drains vmcnt before any frag read
#pragma unroll
        for (int j = 0; j < 4; ++j) {    // compiler software-pipelines + fine lgkm waits (m97)
            long Af[4], Bf[4];
#pragma unroll
            for (int m = 0; m < 4; ++m)
                Af[m] = *(const long*)(LAp + m * 2048 + fbase + slotx[j]);
#pragma unroll
            for (int n = 0; n < 4; ++n)
                Bf[n] = *(const long*)(LBp + n * 2048 + fbase + slotx[j]);
#pragma unroll
            for (int m = 0; m < 4; ++m)
#pragma unroll
                for (int n = 0; n < 4; ++n)
                    acc[m][n] = __builtin_amdgcn_mfma_f32_16x16x32_fp8_fp8(
                                    Af[m], Bf[n], acc[m][n], 0, 0, 0);
        }
        __syncthreads();                 // protect LDS before next tile's staging
    }

    // Epilogue. C/D layout: col = l15, row = lk*4 + r (dtype-independent).
    // acc = (8a)(8b) = 64*cossim -> logits = acc * (20/64).
    const bool dblk = (bi == bj);
    const int rowb = bi * 128 + wr * 64;
    const int colb = bj * 128 + wc * 64;
#pragma unroll
    for (int mi = 0; mi < 4; ++mi) {
#pragma unroll
        for (int r = 0; r < 4; ++r) {
            float s = 0.f;
            int gi = rowb + mi * 16 + lk * 4 + r;
#pragma unroll
            for (int ni = 0; ni < 4; ++ni) {
                float v = acc[mi][ni][r] * (20.0f / 64.0f);
                s += __expf(v);
                if (dblk) {
                    int gj = colb + ni * 16 + l15;
                    if (gi == gj) diag[gi] = v;
                }
            }
#pragma unroll
            for (int off = 1; off < 16; off <<= 1) s += __shfl_xor(s, off);
            if (l15 == 0) atomicAdd(rowsum + gi, s);
        }
    }
}

// ---------------- Kernel 3: loss = mean(log(rowsum) - diag) ----------------
__global__ __launch_bounds__(1024) void k_final(const float* __restrict__ rowsum,
                                                const float* __restrict__ diag,
                                                float* __restrict__ out) {
    int tid = threadIdx.x;
    float s = 0.f;
#pragma unroll
    for (int i = 0; i < 4; ++i) {
        int idx = tid + 1024 * i;
        s += logf(rowsum[idx]) - diag[idx];
    }
#pragma unroll
    for (int off = 32; off; off >>= 1) s += __shfl_xor(s, off);
    __shared__ float red[16];
    if ((tid & 63) == 0) red[tid >> 6] = s;
    __syncthreads();
    if (tid == 0) {
        float tot = 0.f;
#pragma unroll
        for (int i = 0; i < 16; ++i) tot += red[i];
        out[0] = tot * (1.0f / NROWS);
    }
}

extern "C" void kernel_launch(void* const* d_in, const int* in_sizes, int n_in,
                              void* d_out, int out_size, void* d_ws, size_t ws_size,
                              hipStream_t stream) {
    const float* f1 = (const float*)d_in[0];
    const float* f2 = (const float*)d_in[1];
    float* out = (float*)d_out;

    char* ws = (char*)d_ws;                       // layout: n1 | n2 | rowsum | diag
    unsigned char* n1 = (unsigned char*)ws;
    unsigned char* n2 = n1 + (size_t)NROWS * DIM;
    float* rowsum = (float*)(ws + 2 * (size_t)NROWS * DIM);
    float* diag = rowsum + NROWS;

    k_norm<<<2048, 256, 0, stream>>>(f1, f2, n1, n2, rowsum);
    k_gemm_lse<<<1024, 256, 0, stream>>>(n1, n2, rowsum, diag);
    k_final<<<1, 1024, 0, stream>>>(rowsum, diag, out);
}